// Round 6
// baseline (131.188 us; speedup 1.0000x reference)
//
#include <hip/hip_runtime.h>
#include <math.h>

typedef __bf16 bf16_t;
typedef bf16_t bf16x8 __attribute__((ext_vector_type(8)));
typedef float f32x4 __attribute__((ext_vector_type(4)));
typedef unsigned short ushort_t;
typedef unsigned int uint_t;

#define C10L2E 14.4269504088896340736f   // 10 * log2(e)  (scale to log2-logit space)
#define LN2    0.69314718055994530942f
#define NEGL   -1.0e30f                  // -inf in log2-logit space

static __device__ __forceinline__ float fexp2(float x){ return __builtin_amdgcn_exp2f(x); }
static __device__ __forceinline__ float flog2(float x){ return __builtin_amdgcn_logf(x); }

#define GLOAD16(g, l) __builtin_amdgcn_global_load_lds( \
    (const __attribute__((address_space(1))) void*)(g), \
    (__attribute__((address_space(3))) void*)(l), 16, 0, 0)

// ---------------- fp32 -> bf16 (RNE) ----------------
static __device__ __forceinline__ ushort_t f2bf1(float f) {
    uint_t u = __float_as_uint(f);
    uint_t r = (u + 0x7fffu + ((u >> 16) & 1u)) >> 16;
    return (ushort_t)r;
}

// ---------------- prep: bf16 convert + label scatter (fused) ----------------
__global__ void prep_kernel(const float* __restrict__ feat, const int* __restrict__ labels,
                            ushort_t* __restrict__ Fb, int* __restrict__ cnt,
                            int* __restrict__ idxl) {
    int i = blockIdx.x * 256 + threadIdx.x;        // 0..524287 float4s
    float4 f = reinterpret_cast<const float4*>(feat)[i];
    ushort4 o;
    o.x = f2bf1(f.x); o.y = f2bf1(f.y); o.z = f2bf1(f.z); o.w = f2bf1(f.w);
    reinterpret_cast<ushort4*>(Fb)[i] = o;
    if (i < 4096) {
        int lab = labels[i];
        int p = atomicAdd(&cnt[lab], 1);
        if (p < 64) idxl[lab * 64 + p] = i;
    }
}

// ---------------- per-class term: (|G_c|^2 - sum|f_i|^2) / (2*cnt-1) ----------------
// 250 blocks x 256 threads; one wave per class
__global__ void classterm_kernel(const float* __restrict__ feat, const int* __restrict__ cnt,
                                 const int* __restrict__ idxl, float* __restrict__ term) {
    int c = blockIdx.x * 4 + (threadIdx.x >> 6);
    int lane = threadIdx.x & 63;
    int n = cnt[c];
    float4 g4 = make_float4(0.f, 0.f, 0.f, 0.f);
    float n2 = 0.f;
    for (int e = 0; e < n && e < 64; ++e) {
        int r = idxl[c * 64 + e];
        float4 f0 = reinterpret_cast<const float4*>(feat)[(size_t)r * 64 + lane];
        float4 f1 = reinterpret_cast<const float4*>(feat)[(size_t)(r + 4096) * 64 + lane];
        g4.x += f0.x + f1.x; g4.y += f0.y + f1.y;
        g4.z += f0.z + f1.z; g4.w += f0.w + f1.w;
        n2 += f0.x*f0.x + f0.y*f0.y + f0.z*f0.z + f0.w*f0.w
            + f1.x*f1.x + f1.y*f1.y + f1.z*f1.z + f1.w*f1.w;
    }
    float gg = g4.x*g4.x + g4.y*g4.y + g4.z*g4.z + g4.w*g4.w;
    #pragma unroll
    for (int d = 1; d < 64; d <<= 1) {
        gg += __shfl_xor(gg, d, 64);
        n2 += __shfl_xor(n2, d, 64);
    }
    if (lane == 0) term[c] = (n > 0) ? (gg - n2) / (float)(2 * n - 1) : 0.0f;
}

// ---------------- main MFMA kernel: symmetric triangle ----------------
// Grid 2080 = 64*65/2 triangle of 128x128 tiles (I <= J). 256 threads = 4 waves (2x2),
// wave tile 64x64, full K=256 in 4 K-quarter phases. A,B quarters (16KB each) staged
// via global_load_lds, double-buffered -> 64KB LDS -> 2 blocks/CU.
// Off-diagonal blocks reduce acc BOTH ways (rows -> slot J, cols -> slot I): every
// MFMA counted twice => total MFMA work halved vs full 8192^2.
// part[8192][64] float2 (max_log2, sumexp): each slot written by exactly one block.
__global__ __launch_bounds__(256, 2) void supcon_main(
        const ushort_t* __restrict__ Fb, float2* __restrict__ part) {
    extern __shared__ char lds[];   // [0,16K) A0 | [16K,32K) A1 | [32K,48K) B0 | [48K,64K) B1

    const int tid  = threadIdx.x;
    const int lane = tid & 63;
    const int wid  = tid >> 6;
    const int wrow = (wid >> 1) * 64;
    const int wcol = (wid & 1) * 64;
    const int g    = lane >> 4;
    const int l15  = lane & 15;

    // ---- decode triangle (I,J) from blockIdx ----
    int b = blockIdx.x;
    int I = (int)((129.0 - sqrt(16641.0 - 8.0 * (double)b)) * 0.5);
    while (I > 0 && I * (129 - I) / 2 > b) --I;
    while ((I + 1) * (128 - I) / 2 <= b) ++I;      // base(I+1) = (I+1)*(129-(I+1))/2
    const int J = I + (b - I * (129 - I) / 2);
    const int r0 = I * 128;
    const int j0 = J * 128;
    const bool diag = (I == J);

    // ---- staging: quarter q of rows base.. (128 rows x 64 K) into 16KB buffer ----
    // LDS chunk c: row=c>>3, slot s=c&7; holds global k-slot (s ^ (row&7)) [inv swizzle]
    auto stage = [&](int q, int bufi) {
        #pragma unroll
        for (int i = 0; i < 4; ++i) {
            int c = i * 256 + tid;
            int row = c >> 3, s = c & 7;
            size_t off = (size_t)(r0 + row) * 256 + q * 64 + ((s ^ (row & 7)) * 8);
            GLOAD16(Fb + off, lds + bufi * 16384 + c * 16);
        }
        #pragma unroll
        for (int i = 0; i < 4; ++i) {
            int c = i * 256 + tid;
            int row = c >> 3, s = c & 7;
            size_t off = (size_t)(j0 + row) * 256 + q * 64 + ((s ^ (row & 7)) * 8);
            GLOAD16(Fb + off, lds + 32768 + bufi * 16384 + c * 16);
        }
    };

    stage(0, 0);

    f32x4 acc[4][4];
    #pragma unroll
    for (int m = 0; m < 4; ++m)
        #pragma unroll
        for (int n = 0; n < 4; ++n)
            #pragma unroll
            for (int w = 0; w < 4; ++w) acc[m][n][w] = 0.0f;

    #pragma unroll
    for (int p = 0; p < 4; ++p) {
        __syncthreads();                 // drains vmcnt(0): buffer p landed; prev reads done
        if (p < 3) stage(p + 1, (p + 1) & 1);
        const char* Ap = lds + (p & 1) * 16384;
        const char* Bp = lds + 32768 + (p & 1) * 16384;
        #pragma unroll
        for (int kk = 0; kk < 2; ++kk) {
            const int ps = ((kk * 4 + g) ^ (l15 & 7)) * 16;
            bf16x8 a[4], bfr[4];
            #pragma unroll
            for (int m = 0; m < 4; ++m)
                a[m] = *reinterpret_cast<const bf16x8*>(Ap + (wrow + m * 16 + l15) * 128 + ps);
            #pragma unroll
            for (int n = 0; n < 4; ++n)
                bfr[n] = *reinterpret_cast<const bf16x8*>(Bp + (wcol + n * 16 + l15) * 128 + ps);
            #pragma unroll
            for (int m = 0; m < 4; ++m)
                #pragma unroll
                for (int n = 0; n < 4; ++n)
                    acc[m][n] = __builtin_amdgcn_mfma_f32_16x16x32_bf16(a[m], bfr[n], acc[m][n], 0, 0, 0);
        }
    }

    // ---- row epilogue: per (m,v) reduce over 4 cols, then 16-lane shfl merge ----
    float rM[16], rS[16];
    #pragma unroll
    for (int m = 0; m < 4; ++m) {
        #pragma unroll
        for (int v = 0; v < 4; ++v) {
            float x0 = acc[m][0][v] * C10L2E;
            float x1 = acc[m][1][v] * C10L2E;
            float x2 = acc[m][2][v] * C10L2E;
            float x3 = acc[m][3][v] * C10L2E;
            if (diag) {
                int rl = wrow + m * 16 + g * 4 + v;   // local row
                int cb = wcol + l15;                  // local col base
                if (cb      == rl) x0 = NEGL;
                if (cb + 16 == rl) x1 = NEGL;
                if (cb + 32 == rl) x2 = NEGL;
                if (cb + 48 == rl) x3 = NEGL;
            }
            float mx = fmaxf(fmaxf(x0, x1), fmaxf(x2, x3));
            rM[m * 4 + v] = mx;
            rS[m * 4 + v] = fexp2(x0 - mx) + fexp2(x1 - mx) + fexp2(x2 - mx) + fexp2(x3 - mx);
        }
    }
    #pragma unroll
    for (int idx = 0; idx < 16; ++idx) {
        float m_ = rM[idx], s_ = rS[idx];
        #pragma unroll
        for (int d = 1; d < 16; d <<= 1) {
            float mo = __shfl_xor(m_, d, 64);
            float so = __shfl_xor(s_, d, 64);
            float nm = fmaxf(m_, mo);
            s_ = s_ * fexp2(m_ - nm) + so * fexp2(mo - nm);
            m_ = nm;
        }
        rM[idx] = m_; rS[idx] = s_;
    }

    // ---- col epilogue (off-diag): per n reduce over 16 in-lane rows, then g-merge ----
    float cM[4], cS[4];
    if (!diag) {
        #pragma unroll
        for (int n = 0; n < 4; ++n) {
            float mx = -3.0e38f;
            #pragma unroll
            for (int m = 0; m < 4; ++m)
                #pragma unroll
                for (int v = 0; v < 4; ++v)
                    mx = fmaxf(mx, acc[m][n][v]);
            mx *= C10L2E;
            float s = 0.0f;
            #pragma unroll
            for (int m = 0; m < 4; ++m)
                #pragma unroll
                for (int v = 0; v < 4; ++v)
                    s += fexp2(fmaf(acc[m][n][v], C10L2E, -mx));
            float m_ = mx;
            #pragma unroll
            for (int d = 16; d < 64; d <<= 1) {
                float mo = __shfl_xor(m_, d, 64);
                float so = __shfl_xor(s, d, 64);
                float nm = fmaxf(m_, mo);
                s = s * fexp2(m_ - nm) + so * fexp2(mo - nm);
                m_ = nm;
            }
            cM[n] = m_; cS[n] = s;
        }
    }

    // ---- pairwise wave merges through LDS, then part writes ----
    float2* mrg = (float2*)lds;   // [0..127] rows, [128..255] cols (2KB, reuses A0)
    __syncthreads();
    if ((wid & 1) == 1 && l15 == 0) {        // waves 1,3: publish row states
        #pragma unroll
        for (int idx = 0; idx < 16; ++idx) {
            float2 v; v.x = rM[idx]; v.y = rS[idx];
            mrg[wrow + (idx >> 2) * 16 + g * 4 + (idx & 3)] = v;
        }
    }
    if (!diag && wid >= 2 && lane < 16) {    // waves 2,3: publish col states
        #pragma unroll
        for (int n = 0; n < 4; ++n) {
            float2 v; v.x = cM[n]; v.y = cS[n];
            mrg[128 + wcol + n * 16 + lane] = v;
        }
    }
    __syncthreads();
    if ((wid & 1) == 0 && l15 == 0) {        // waves 0,2: merge rows -> part[r][J]
        #pragma unroll
        for (int idx = 0; idx < 16; ++idx) {
            int row = wrow + (idx >> 2) * 16 + g * 4 + (idx & 3);
            float2 o = mrg[row];
            float nm = fmaxf(rM[idx], o.x);
            float2 v;
            v.x = nm;
            v.y = rS[idx] * fexp2(rM[idx] - nm) + o.y * fexp2(o.x - nm);
            part[(size_t)(r0 + row) * 64 + J] = v;
        }
    }
    if (!diag && wid < 2 && lane < 16) {     // waves 0,1: merge cols -> part[c][I]
        #pragma unroll
        for (int n = 0; n < 4; ++n) {
            int col = wcol + n * 16 + lane;
            float2 o = mrg[128 + col];
            float nm = fmaxf(cM[n], o.x);
            float2 v;
            v.x = nm;
            v.y = cS[n] * fexp2(cM[n] - nm) + o.y * fexp2(o.x - nm);
            part[(size_t)(j0 + col) * 64 + I] = v;
        }
    }
}

// ---------------- combine + final: merge 64 slots/row -> lse; atomic total; last block writes ----
// 2048 blocks x 256 threads; one wave per row (4 rows/block)
__global__ void combine_kernel(const float2* __restrict__ part, const float* __restrict__ term,
                               float* __restrict__ acc, int* __restrict__ cntr,
                               float* __restrict__ out) {
    __shared__ float sm[4];
    int tid = threadIdx.x;
    int r = blockIdx.x * 4 + (tid >> 6);
    int lane = tid & 63;
    float2 v = part[(size_t)r * 64 + lane];
    float m_ = v.x, s_ = v.y;
    #pragma unroll
    for (int d = 1; d < 64; d <<= 1) {
        float mo = __shfl_xor(m_, d, 64);
        float so = __shfl_xor(s_, d, 64);
        float nm = fmaxf(m_, mo);
        s_ = s_ * fexp2(m_ - nm) + so * fexp2(mo - nm);
        m_ = nm;
    }
    if (lane == 0) sm[tid >> 6] = LN2 * (m_ + flog2(s_));
    __syncthreads();
    if (tid == 0) {
        float a = sm[0] + sm[1] + sm[2] + sm[3];
        if (blockIdx.x < 1000) a -= 10.0f * term[blockIdx.x];
        atomicAdd(acc, a);
        __threadfence();
        int old = atomicAdd(cntr, 1);
        if (old == 2047) {
            __threadfence();
            float tot = atomicAdd(acc, 0.0f);
            out[0] = tot * (0.1f / 8192.0f);
        }
    }
}

extern "C" void kernel_launch(void* const* d_in, const int* in_sizes, int n_in,
                              void* d_out, int out_size, void* d_ws, size_t ws_size,
                              hipStream_t stream) {
    const float* feat = (const float*)d_in[0];    // 8192 x 256 fp32
    const int* labels = (const int*)d_in[1];      // 4096
    float* out = (float*)d_out;

    char* ws = (char*)d_ws;
    ushort_t* Fb = (ushort_t*)ws;                                // 4 MB
    float2* part = (float2*)(ws + (4u << 20));                   // 4 MB (8192 x 64 x 8B)
    int* cnt     = (int*)(ws + (8u << 20));                      // 4 KB
    float* acc   = (float*)(ws + (8u << 20) + 4096);             // 4 B
    int* cntr    = (int*)(ws + (8u << 20) + 4100);               // 4 B
    int* idxl    = (int*)(ws + (8u << 20) + 8192);               // 256 KB
    float* term  = (float*)(ws + (8u << 20) + 8192 + 262144);    // 4 KB

    hipMemsetAsync(ws + (8u << 20), 0, 8192, stream);            // cnt + acc + cntr
    prep_kernel<<<2048, 256, 0, stream>>>(feat, labels, Fb, cnt, idxl);
    classterm_kernel<<<250, 256, 0, stream>>>(feat, cnt, idxl, term);
    supcon_main<<<2080, 256, 65536, stream>>>(Fb, part);
    combine_kernel<<<2048, 256, 0, stream>>>(part, term, acc, cntr, out);
}

// Round 7
// 92.178 us; speedup vs baseline: 1.4232x; 1.4232x over previous
//
#include <hip/hip_runtime.h>

typedef __bf16 bf16_t;
typedef bf16_t bf16x8 __attribute__((ext_vector_type(8)));
typedef float f32x4 __attribute__((ext_vector_type(4)));
typedef unsigned short ushort_t;
typedef unsigned int uint_t;

#define C10L2E 14.4269504088896340736f   // 10 * log2(e)
#define LN2    0.69314718055994530942f
#define NEG_BIG -3.0e38f
#define M0     -1.0e30f
#define THR_L2 11.5415603f               // 0.8 raw logit units in log2-space

static __device__ __forceinline__ float fexp2(float x){ return __builtin_amdgcn_exp2f(x); }
static __device__ __forceinline__ float flog2(float x){ return __builtin_amdgcn_logf(x); }

#define GLOAD16(g, l) __builtin_amdgcn_global_load_lds( \
    (const __attribute__((address_space(1))) void*)(g), \
    (__attribute__((address_space(3))) void*)(l), 16, 0, 0)

#define WAITV(n) asm volatile("s_waitcnt vmcnt(" #n ")" ::: "memory")

// ---------------- fp32 -> bf16 (RNE) ----------------
static __device__ __forceinline__ ushort_t f2bf1(float f) {
    uint_t u = __float_as_uint(f);
    uint_t r = (u + 0x7fffu + ((u >> 16) & 1u)) >> 16;
    return (ushort_t)r;
}

// ---------------- prep: bf16 convert + label scatter (fused) ----------------
__global__ void prep_kernel(const float* __restrict__ feat, const int* __restrict__ labels,
                            ushort_t* __restrict__ Fb, int* __restrict__ cnt,
                            int* __restrict__ idxl) {
    int i = blockIdx.x * 256 + threadIdx.x;        // 0..524287 float4s
    float4 f = reinterpret_cast<const float4*>(feat)[i];
    ushort4 o;
    o.x = f2bf1(f.x); o.y = f2bf1(f.y); o.z = f2bf1(f.z); o.w = f2bf1(f.w);
    reinterpret_cast<ushort4*>(Fb)[i] = o;
    if (i < 4096) {
        int lab = labels[i];
        int p = atomicAdd(&cnt[lab], 1);
        if (p < 64) idxl[lab * 64 + p] = i;
    }
}

// ---------------- per-class term: (|G_c|^2 - sum|f_i|^2) / (2*cnt-1) ----------------
// 250 blocks x 256 threads; one wave per class
__global__ void classterm_kernel(const float* __restrict__ feat, const int* __restrict__ cnt,
                                 const int* __restrict__ idxl, float* __restrict__ term) {
    int c = blockIdx.x * 4 + (threadIdx.x >> 6);
    int lane = threadIdx.x & 63;
    int n = cnt[c];
    float4 g4 = make_float4(0.f, 0.f, 0.f, 0.f);
    float n2 = 0.f;
    for (int e = 0; e < n && e < 64; ++e) {
        int r = idxl[c * 64 + e];
        float4 f0 = reinterpret_cast<const float4*>(feat)[(size_t)r * 64 + lane];
        float4 f1 = reinterpret_cast<const float4*>(feat)[(size_t)(r + 4096) * 64 + lane];
        g4.x += f0.x + f1.x; g4.y += f0.y + f1.y;
        g4.z += f0.z + f1.z; g4.w += f0.w + f1.w;
        n2 += f0.x*f0.x + f0.y*f0.y + f0.z*f0.z + f0.w*f0.w
            + f1.x*f1.x + f1.y*f1.y + f1.z*f1.z + f1.w*f1.w;
    }
    float gg = g4.x*g4.x + g4.y*g4.y + g4.z*g4.z + g4.w*g4.w;
    #pragma unroll
    for (int d = 1; d < 64; d <<= 1) {
        gg += __shfl_xor(gg, d, 64);
        n2 += __shfl_xor(n2, d, 64);
    }
    if (lane == 0) term[c] = (n > 0) ? (gg - n2) / (float)(2 * n - 1) : 0.0f;
}

// ---------------- main MFMA kernel ----------------
// Grid (128,4) = 512 blocks = 2/CU. 256 threads = 4 waves (1 row-group x 4 col-groups),
// wave tile 64x64. Block: rows r0..r0+63, cols c0..c0+2047 (8 col-tiles x 8 K-eighths
// = 64 phases). LDS 80KB: A full-K (64x256 bf16, 32KB, staged once, shared by all
// 4 waves) + 3 rotating 16KB B K-eighth buffers (depth-2 prefetch, counted vmcnt(4),
// stage issued AFTER the barrier so rotation guarantees write-after-read).
// 2 blocks/CU -> two independent barrier groups overlap LDS and MFMA pipes.
__global__ __launch_bounds__(256, 2) void supcon_main(
        const ushort_t* __restrict__ Fb, float2* __restrict__ part) {
    extern __shared__ char lds[];
    char* As = lds;                     // [64 rows][32 slots of 16B], slot^=(row&31)
    char* Bb = lds + 32768;             // 3 x [256 cols][4 slots of 16B], slot^=((col>>2)&3)

    const int tid  = threadIdx.x;
    const int lane = tid & 63;
    const int wid  = tid >> 6;
    const int wcol = wid * 64;
    const int g    = lane >> 4;
    const int l15  = lane & 15;
    const int r0 = blockIdx.x * 64;
    const int c0 = blockIdx.y * 2048;

    // ---- stage A once (8 chunks/thread) ----
    #pragma unroll
    for (int i = 0; i < 8; ++i) {
        int c = i * 256 + tid;                     // 0..2047
        int row = c >> 5, sl = c & 31;
        int s = sl ^ (row & 31);                   // inverse swizzle on source
        GLOAD16(Fb + (size_t)(r0 + row) * 256 + s * 8, As + c * 16);
    }

    // ---- B staging geometry (4 chunks/thread) ----
    int bofs[4], bdst[4];
    #pragma unroll
    for (int i = 0; i < 4; ++i) {
        int c = i * 256 + tid;                     // 0..1023
        int col = c >> 2, sl = c & 3;
        int s = sl ^ ((col >> 2) & 3);
        bofs[i] = col * 256 + s * 8;               // element offset within col-tile
        bdst[i] = c * 16;
    }
    auto stageB = [&](int p) {                     // phase 0..63: t=p>>3, e=p&7, buf=p%3
        const ushort_t* base = Fb + (size_t)(c0 + (p >> 3) * 256) * 256 + (p & 7) * 32;
        char* Bd = Bb + (p % 3) * 16384;
        #pragma unroll
        for (int i = 0; i < 4; ++i)
            GLOAD16(base + bofs[i], Bd + bdst[i]);
    };

    stageB(0); stageB(1);

    float ML2[16], S[16];
    #pragma unroll
    for (int x = 0; x < 16; ++x) { ML2[x] = M0; S[x] = 0.0f; }

    f32x4 acc[4][4];

    #pragma unroll 1
    for (int t = 0; t < 8; ++t) {
        #pragma unroll
        for (int e = 0; e < 8; ++e) {
            const int p = t * 8 + e;
            // counted wait: my buffer's loads (issued 2 phases ago) are done
            if (p < 63) { WAITV(4); } else { WAITV(0); }
            __builtin_amdgcn_s_barrier();
            __builtin_amdgcn_sched_barrier(0);
            // issue next-next stage (writes buf (p+2)%3 == (p-1)%3, readers done)
            if (p + 2 < 64) stageB(p + 2);

            // ---- ds reads: 4 A + 4 B b128 per lane ----
            bf16x8 a[4], b[4];
            const int sA = e * 4 + g;
            #pragma unroll
            for (int m = 0; m < 4; ++m) {
                int row = m * 16 + l15;
                int phys = sA ^ (row & 31);
                a[m] = *reinterpret_cast<const bf16x8*>(As + row * 512 + phys * 16);
            }
            const char* Bp = Bb + (p % 3) * 16384;
            #pragma unroll
            for (int n = 0; n < 4; ++n) {
                int col = wcol + n * 16 + l15;
                int phys = g ^ ((col >> 2) & 3);
                b[n] = *reinterpret_cast<const bf16x8*>(Bp + col * 64 + phys * 16);
            }

            if (e == 0) {
                #pragma unroll
                for (int m = 0; m < 4; ++m)
                    #pragma unroll
                    for (int n = 0; n < 4; ++n)
                        #pragma unroll
                        for (int w = 0; w < 4; ++w) acc[m][n][w] = 0.0f;
            }
            #pragma unroll
            for (int m = 0; m < 4; ++m)
                #pragma unroll
                for (int n = 0; n < 4; ++n)
                    acc[m][n] = __builtin_amdgcn_mfma_f32_16x16x32_bf16(a[m], b[n], acc[m][n], 0, 0, 0);

            if (e == 7) {
                const int jt = c0 + t * 256;
                const bool diag = (jt == (r0 & ~255));
                const int jc = jt + wcol + l15;
                #pragma unroll
                for (int m = 0; m < 4; ++m) {
                    #pragma unroll
                    for (int v = 0; v < 4; ++v) {
                        const int idx = m * 4 + v;
                        float x0 = acc[m][0][v], x1 = acc[m][1][v];
                        float x2 = acc[m][2][v], x3 = acc[m][3][v];
                        if (diag) {
                            int i = r0 + m * 16 + g * 4 + v;
                            if (jc      == i) x0 = NEG_BIG;
                            if (jc + 16 == i) x1 = NEG_BIG;
                            if (jc + 32 == i) x2 = NEG_BIG;
                            if (jc + 48 == i) x3 = NEG_BIG;
                        }
                        float tm = fmaxf(fmaxf(x0, x1), fmaxf(x2, x3));
                        float cc = tm * C10L2E;
                        float ml = ML2[idx];
                        if (cc > ml + THR_L2) {          // rare rescale (defer-max)
                            S[idx] *= fexp2(ml - cc);
                            ml = cc;
                            ML2[idx] = cc;
                        }
                        S[idx] += fexp2(fmaf(x0, C10L2E, -ml)) + fexp2(fmaf(x1, C10L2E, -ml))
                                + fexp2(fmaf(x2, C10L2E, -ml)) + fexp2(fmaf(x3, C10L2E, -ml));
                    }
                }
            }
        }
    }

    // ---- cross-lane merge within 16-lane groups, store partials ----
    const int slot = blockIdx.y * 4 + wid;           // 16 slots per row
    #pragma unroll
    for (int idx = 0; idx < 16; ++idx) {
        float m_ = ML2[idx], s_ = S[idx];
        #pragma unroll
        for (int d = 1; d < 16; d <<= 1) {
            float mo = __shfl_xor(m_, d, 64);
            float so = __shfl_xor(s_, d, 64);
            float nm = fmaxf(m_, mo);
            s_ = s_ * fexp2(m_ - nm) + so * fexp2(mo - nm);
            m_ = nm;
        }
        if (l15 == 0) {
            int i = r0 + (idx >> 2) * 16 + g * 4 + (idx & 3);
            float2 val; val.x = m_; val.y = s_;
            part[(size_t)i * 16 + slot] = val;
        }
    }
}

// ---------------- combine + final (fused): lse merge, class terms, last-block writes out ----
// 512 blocks x 256 threads; 16 rows/block, 16 slots/row
__global__ void combine_kernel(const float2* __restrict__ part, const float* __restrict__ term,
                               float* __restrict__ acc, int* __restrict__ cntr,
                               float* __restrict__ out) {
    __shared__ float sm[16];
    int tid = threadIdx.x;
    int row = blockIdx.x * 16 + (tid >> 4);
    int l16 = tid & 15;
    float2 v = part[(size_t)row * 16 + l16];
    float m_ = v.x, s_ = v.y;
    #pragma unroll
    for (int d = 1; d < 16; d <<= 1) {
        float mo = __shfl_xor(m_, d, 64);
        float so = __shfl_xor(s_, d, 64);
        float nm = fmaxf(m_, mo);
        s_ = s_ * fexp2(m_ - nm) + so * fexp2(mo - nm);
        m_ = nm;
    }
    if (l16 == 0) sm[tid >> 4] = LN2 * (m_ + flog2(s_));
    __syncthreads();
    if (tid == 0) {
        float a = 0.f;
        #pragma unroll
        for (int i = 0; i < 16; ++i) a += sm[i];
        a -= 10.0f * term[blockIdx.x];
        if (blockIdx.x < 488) a -= 10.0f * term[512 + blockIdx.x];
        atomicAdd(acc, a);
        __threadfence();
        int old = atomicAdd(cntr, 1);
        if (old == 511) {
            __threadfence();
            float tot = atomicAdd(acc, 0.0f);
            out[0] = tot * (0.1f / 8192.0f);
        }
    }
}

extern "C" void kernel_launch(void* const* d_in, const int* in_sizes, int n_in,
                              void* d_out, int out_size, void* d_ws, size_t ws_size,
                              hipStream_t stream) {
    const float* feat = (const float*)d_in[0];    // 8192 x 256 fp32
    const int* labels = (const int*)d_in[1];      // 4096
    float* out = (float*)d_out;

    char* ws = (char*)d_ws;
    ushort_t* Fb = (ushort_t*)ws;                                // 4 MB
    float2* part = (float2*)(ws + (4u << 20));                   // 1 MB (8192 x 16 x 8B)
    int* cnt     = (int*)(ws + (5u << 20));                      // 4 KB
    float* acc   = (float*)(ws + (5u << 20) + 4096);             // 4 B
    int* cntr    = (int*)(ws + (5u << 20) + 4100);               // 4 B
    int* idxl    = (int*)(ws + (5u << 20) + 8192);               // 256 KB
    float* term  = (float*)(ws + (5u << 20) + 8192 + 262144);    // 4 KB

    hipMemsetAsync(ws + (5u << 20), 0, 8192, stream);            // cnt + acc + cntr
    prep_kernel<<<2048, 256, 0, stream>>>(feat, labels, Fb, cnt, idxl);
    classterm_kernel<<<250, 256, 0, stream>>>(feat, cnt, idxl, term);
    dim3 grid(128, 4);
    supcon_main<<<grid, 256, 81920, stream>>>(Fb, part);
    combine_kernel<<<512, 256, 0, stream>>>(part, term, acc, cntr, out);
}